// Round 8
// baseline (415.664 us; speedup 1.0000x reference)
//
#include <hip/hip_runtime.h>
#include <hip/hip_bf16.h>

#define B_SZ 16
#define C_IN 256
#define N_SP 2304
#define K_INT 128
#define NT64 36   // 64-wide n tiles
#define MI 18     // attn m-iters (tile 128)

typedef __attribute__((ext_vector_type(8))) short short8;
typedef __attribute__((ext_vector_type(4))) float f32x4;
typedef __attribute__((ext_vector_type(16))) float f32x16;

// packed fp32x2 -> bf16x2 (v_cvt_pk_bf16_f32, RNE)
__device__ inline unsigned pk_bf16(float a, float b) {
  float2 f; f.x = a; f.y = b;
  __hip_bfloat162 h = __float22bfloat162_rn(f);
  unsigned u;
  __builtin_memcpy(&u, &h, sizeof(u));
  return u;
}

// ---------------------------------------------------------------------------
// Fragment layouts (1KB frags, element = frag*512 + lane*8 + j):
//  Qf/Kf: frag(b, nt=n/32, ks=k/16): elem = M[nt*32+(lane&31)][ks*16+(lane>>5)*8+j]
//  Gf:    frag(b, ct=c/32, ms=m/16): elem = G[ct*32+(lane&31)][ms*16+(lane>>5)*8+j]
// ---------------------------------------------------------------------------

// xcast: stream x (fp32, coalesced 4KB/wave reads) -> Gf bf16 frag layout.
__global__ __launch_bounds__(256) void xcast_kernel(
    const float* __restrict__ x, short* __restrict__ Gf)
{
  const int tid = blockIdx.x * 256 + threadIdx.x;   // 16*256*144 threads
  const int mc  = tid % 144;                        // 16-wide m chunk
  const int row = tid / 144;                        // b*256 + c
  const int c   = row & 255, b = row >> 8;

  const float* xp = x + (size_t)row * N_SP + mc * 16;
  unsigned u[8];
#pragma unroll
  for (int i = 0; i < 4; ++i) {
    float4 v = ((const float4*)xp)[i];
    u[2*i]   = pk_bf16(v.x, v.y);
    u[2*i+1] = pk_bf16(v.z, v.w);
  }
  short* fb = Gf + ((size_t)(b * 8 + (c >> 5)) * 144 + mc) * 512 + (c & 31) * 8;
  uint4 lo; lo.x = u[0]; lo.y = u[1]; lo.z = u[2]; lo.w = u[3];
  uint4 hi; hi.x = u[4]; hi.y = u[5]; hi.z = u[6]; hi.w = u[7];
  *(uint4*)fb = lo;            // m = mc*16 + 0..7   (h=0 half)
  *(uint4*)(fb + 256) = hi;    // m = mc*16 + 8..15  (h=1 half)
}

// ---------------------------------------------------------------------------
// proj: Qf/Kf = frag-layout bf16 of (W x + bias). Reads x via Gf frags.
// ---------------------------------------------------------------------------
__global__ __launch_bounds__(256) void proj_kernel(
    const short* __restrict__ Gf,
    const float* __restrict__ theta_w, const float* __restrict__ theta_b,
    const float* __restrict__ phi_w,   const float* __restrict__ phi_b,
    short* __restrict__ Qf, short* __restrict__ Kf)
{
  __shared__ short Xl[64][264];  // [n][c], +8 pad

  const int b  = blockIdx.x / NT64;
  const int n0 = (blockIdx.x % NT64) * 64;
  const int t  = threadIdx.x;
  const int wave = t >> 6, lane = t & 63;
  const int l31 = lane & 31, h = lane >> 5;

  // ---- phase A: read 8 Gf frags/wave (coalesced), scatter to Xl[n][c] ----
#pragma unroll
  for (int i = 0; i < 2; ++i) {
    const int cgrp = wave * 2 + i;
    const int c = cgrp * 32 + l31;
#pragma unroll
    for (int s = 0; s < 4; ++s) {
      const short* fb = Gf + ((size_t)(b * 8 + cgrp) * 144 + (n0 >> 4) + s) * 512 + lane * 8;
      short8 v = *(const short8*)fb;
      const int nl = s * 16 + h * 8;
#pragma unroll
      for (int j = 0; j < 8; ++j) Xl[nl + j][c] = v[j];
    }
  }
  __syncthreads();

  // ---- GEMM: C[k][n] = W[k][:]·X[:][n], 16x16x32, wave owns 32 k-rows ----
  const int col = lane & 15, quad = lane >> 4;

  f32x4 acc[2][2][4];
#pragma unroll
  for (int p = 0; p < 2; ++p)
#pragma unroll
    for (int kr = 0; kr < 2; ++kr)
#pragma unroll
      for (int j = 0; j < 4; ++j) {
        acc[p][kr][j][0] = 0.f; acc[p][kr][j][1] = 0.f;
        acc[p][kr][j][2] = 0.f; acc[p][kr][j][3] = 0.f;
      }

#pragma unroll
  for (int cs = 0; cs < 8; ++cs) {
    const int c0 = cs * 32;
    short8 afr[2][2];
#pragma unroll
    for (int p = 0; p < 2; ++p) {
      const float* W = p ? phi_w : theta_w;
#pragma unroll
      for (int kr = 0; kr < 2; ++kr) {
        const int k = wave * 32 + kr * 16 + col;
        const float* wp = W + (size_t)k * C_IN + c0 + quad * 8;
        float4 w0 = ((const float4*)wp)[0];
        float4 w1 = ((const float4*)wp)[1];
        unsigned u[4];
        u[0] = pk_bf16(w0.x, w0.y); u[1] = pk_bf16(w0.z, w0.w);
        u[2] = pk_bf16(w1.x, w1.y); u[3] = pk_bf16(w1.z, w1.w);
        short8 a;
        __builtin_memcpy(&a, u, sizeof(a));
        afr[p][kr] = a;
      }
    }
#pragma unroll
    for (int j = 0; j < 4; ++j) {
      short8 bfr = *(const short8*)&Xl[j * 16 + col][c0 + quad * 8];
#pragma unroll
      for (int p = 0; p < 2; ++p)
#pragma unroll
        for (int kr = 0; kr < 2; ++kr)
          acc[p][kr][j] = __builtin_amdgcn_mfma_f32_16x16x32_bf16(
              afr[p][kr], bfr, acc[p][kr][j], 0, 0, 0);
    }
  }

  // ---- epilogue: bias + store in 32x32 fragment order (R7-verified) ----
#pragma unroll
  for (int p = 0; p < 2; ++p) {
    const float* bias = p ? phi_b : theta_b;
    short* dst = p ? Kf : Qf;
#pragma unroll
    for (int kr = 0; kr < 2; ++kr) {
      const int ks = wave * 2 + kr;
      const int k0 = wave * 32 + kr * 16 + quad * 4;
      float4 bv = *(const float4*)(bias + k0);
#pragma unroll
      for (int j = 0; j < 4; ++j) {
        f32x4 v = acc[p][kr][j];
        uint2 sv;
        sv.x = pk_bf16(v[0] + bv.x, v[1] + bv.y);
        sv.y = pk_bf16(v[2] + bv.z, v[3] + bv.w);
        size_t addr = ((size_t)(b * 72 + (n0 >> 5) + (j >> 1)) * 8 + ks) * 512
                    + ((j & 1) * 16 + col + 32 * (quad >> 1)) * 8 + (quad & 1) * 4;
        *(uint2*)(dst + addr) = sv;
      }
    }
  }
}

// ---------------------------------------------------------------------------
// attn v3: block = 64 q-rows, 4 waves, m-tile 128 (18 iters).
// Wave w: S for m-quarter w (q64 x m32, 2 held Q-frags x 8 K loads, 16 mfma);
// P exchanged via double-buffered LDS [q64][m128]; PV for c-quarter w
// (q64 x c64 over m128: 16 G loads, 32 mfma). Zero duplicate global loads.
// ---------------------------------------------------------------------------
__global__ __launch_bounds__(256) void attn_kernel(
    const short* __restrict__ Qf, const short* __restrict__ Kf,
    const short* __restrict__ Gf, float* __restrict__ out)
{
  __shared__ short Pl[2][64][132];  // 33792 B, stride 132 (b64-clean, 4-way max)
  __shared__ float Ls[4][64];
  __shared__ float Linv[64];

  const int b   = blockIdx.x / NT64;
  const int qt  = blockIdx.x % NT64;
  const int qn0 = qt * 64;
  const int t = threadIdx.x, w = t >> 6, lane = t & 63;
  const int l31 = lane & 31, h = lane >> 5;

  // Q A-frags (q64 x k128), identical across waves (L1 broadcast)
  short8 qf[2][8];
  {
    const short* qb = Qf + ((size_t)(b * 72 + qt * 2) * 8) * 512 + lane * 8;
#pragma unroll
    for (int qj = 0; qj < 2; ++qj)
#pragma unroll
      for (int ks = 0; ks < 8; ++ks)
        qf[qj][ks] = *(const short8*)(qb + (qj * 8 + ks) * 512);
  }

  f32x16 yacc[2][2];  // [ct][qj]
#pragma unroll
  for (int a = 0; a < 2; ++a)
#pragma unroll
    for (int bb = 0; bb < 2; ++bb)
#pragma unroll
      for (int r = 0; r < 16; ++r) yacc[a][bb][r] = 0.f;
  float lsum[2][16];
#pragma unroll
  for (int qj = 0; qj < 2; ++qj)
#pragma unroll
    for (int r = 0; r < 16; ++r) lsum[qj][r] = 0.f;

  const short* kwb = Kf + (size_t)(b * 72) * 8 * 512 + lane * 8;
  const short* gwb = Gf + (size_t)(b * 8) * 144 * 512 + lane * 8;
  const float SC2 = 0.12754859f;  // (1/sqrt(128)) * log2(e)

  for (int mt = 0; mt < MI; ++mt) {
    const int buf = mt & 1;

    // ---- S: q64 x m32 (this wave's m-quarter) ----
    f32x16 s[2];
#pragma unroll
    for (int qj = 0; qj < 2; ++qj)
#pragma unroll
      for (int r = 0; r < 16; ++r) s[qj][r] = 0.f;
    const short* kf = kwb + (size_t)((mt * 4 + w) * 8) * 512;
#pragma unroll
    for (int ks = 0; ks < 8; ++ks) {
      short8 kb = *(const short8*)(kf + ks * 512);
      s[0] = __builtin_amdgcn_mfma_f32_32x32x16_bf16(qf[0][ks], kb, s[0], 0, 0, 0);
      s[1] = __builtin_amdgcn_mfma_f32_32x32x16_bf16(qf[1][ks], kb, s[1], 0, 0, 0);
    }

    // ---- exp + P write (C-layout -> Pl[q][m], this wave's m32 columns) ----
    const int mloc = w * 32 + l31;
#pragma unroll
    for (int qj = 0; qj < 2; ++qj)
#pragma unroll
      for (int r = 0; r < 16; ++r) {
        float p = exp2f(s[qj][r] * SC2);
        lsum[qj][r] += p;
        const int q = qj * 32 + 4 * h + (r & 3) + 8 * (r >> 2);
        Pl[buf][q][mloc] = (short)(pk_bf16(p, p) & 0xffff);
      }
    __syncthreads();

    // ---- PV: q64 x c64 (this wave's c-quarter) over m128 ----
#pragma unroll
    for (int ms = 0; ms < 8; ++ms) {
      short8 pfr[2];
#pragma unroll
      for (int qj = 0; qj < 2; ++qj) {
        const short* pp = &Pl[buf][qj * 32 + l31][ms * 16 + h * 8];
        uint2 lo = *(const uint2*)pp;
        uint2 hi = *(const uint2*)(pp + 4);
        unsigned uu[4] = {lo.x, lo.y, hi.x, hi.y};
        short8 pf;
        __builtin_memcpy(&pf, uu, sizeof(pf));
        pfr[qj] = pf;
      }
#pragma unroll
      for (int ct = 0; ct < 2; ++ct) {
        const short* gfp = gwb + (size_t)((w * 2 + ct) * 144 + mt * 8 + ms) * 512;
        short8 gb = *(const short8*)gfp;
        yacc[ct][0] = __builtin_amdgcn_mfma_f32_32x32x16_bf16(pfr[0], gb, yacc[ct][0], 0, 0, 0);
        yacc[ct][1] = __builtin_amdgcn_mfma_f32_32x32x16_bf16(pfr[1], gb, yacc[ct][1], 0, 0, 0);
      }
    }
  }

  // ---- row-sum finalize: reduce over m-lanes, then across waves ----
#pragma unroll
  for (int off = 1; off < 32; off <<= 1)
#pragma unroll
    for (int qj = 0; qj < 2; ++qj)
#pragma unroll
      for (int r = 0; r < 16; ++r) lsum[qj][r] += __shfl_xor(lsum[qj][r], off);
  if (l31 == 0) {
#pragma unroll
    for (int qj = 0; qj < 2; ++qj)
#pragma unroll
      for (int r = 0; r < 16; ++r)
        Ls[w][qj * 32 + 4 * h + (r & 3) + 8 * (r >> 2)] = lsum[qj][r];
  }
  __syncthreads();
  if (t < 64) Linv[t] = 1.0f / (Ls[0][t] + Ls[1][t] + Ls[2][t] + Ls[3][t]);
  __syncthreads();

  // ---- store: float4 along n per (ct, qj, g); c scattered per lane ----
#pragma unroll
  for (int qj = 0; qj < 2; ++qj)
#pragma unroll
    for (int g = 0; g < 4; ++g) {
      const int nl = qj * 32 + 4 * h + 8 * g;
      float4 iv;
      iv.x = Linv[nl]; iv.y = Linv[nl + 1]; iv.z = Linv[nl + 2]; iv.w = Linv[nl + 3];
#pragma unroll
      for (int ct = 0; ct < 2; ++ct) {
        const int c = (w * 2 + ct) * 32 + l31;
        float4 v;
        v.x = yacc[ct][qj][4*g+0] * iv.x;
        v.y = yacc[ct][qj][4*g+1] * iv.y;
        v.z = yacc[ct][qj][4*g+2] * iv.z;
        v.w = yacc[ct][qj][4*g+3] * iv.w;
        *(float4*)(out + ((size_t)b * C_IN + c) * N_SP + qn0 + nl) = v;
      }
    }
}

extern "C" void kernel_launch(void* const* d_in, const int* in_sizes, int n_in,
                              void* d_out, int out_size, void* d_ws, size_t ws_size,
                              hipStream_t stream) {
  const float* x  = (const float*)d_in[0];
  const float* tw = (const float*)d_in[1];
  const float* tb = (const float*)d_in[2];
  const float* pw = (const float*)d_in[3];
  const float* pb = (const float*)d_in[4];
  float* out = (float*)d_out;

  // workspace: Qf (9.4MB) | Kf (9.4MB) | Gf (18.9MB) = 37.75 MB
  short* Qf = (short*)d_ws;
  short* Kf = Qf + (size_t)B_SZ * 72 * 8 * 512;
  short* Gf = Kf + (size_t)B_SZ * 72 * 8 * 512;

  xcast_kernel<<<(B_SZ * C_IN * 144) / 256, 256, 0, stream>>>(x, Gf);
  proj_kernel<<<B_SZ * NT64, 256, 0, stream>>>(Gf, tw, tb, pw, pb, Qf, Kf);
  attn_kernel<<<B_SZ * NT64, 256, 0, stream>>>(Qf, Kf, Gf, out);
}

// Round 9
// 368.910 us; speedup vs baseline: 1.1267x; 1.1267x over previous
//
#include <hip/hip_runtime.h>
#include <hip/hip_bf16.h>

#define B_SZ 16
#define C_IN 256
#define N_SP 2304
#define K_INT 128
#define NT64 36   // 64-wide n tiles
#define MI 18     // attn m-iters (tile 128)

typedef __attribute__((ext_vector_type(8))) short short8;
typedef __attribute__((ext_vector_type(4))) float f32x4;
typedef __attribute__((ext_vector_type(16))) float f32x16;

// packed fp32x2 -> bf16x2 (v_cvt_pk_bf16_f32, RNE)
__device__ inline unsigned pk_bf16(float a, float b) {
  float2 f; f.x = a; f.y = b;
  __hip_bfloat162 h = __float22bfloat162_rn(f);
  unsigned u;
  __builtin_memcpy(&u, &h, sizeof(u));
  return u;
}

// XCD-affinity remap: batch b -> blockIdx = b (mod 8)  [heuristic: XCD = blk%8]
__device__ inline void remap_bq(int i, int& b, int& nt) {
  int ii = (i >= 288) ? i - 288 : i;
  b = (ii & 7) + ((i >= 288) ? 8 : 0);
  nt = ii >> 3;
}

// ---------------------------------------------------------------------------
// Fragment layouts (1KB frags, element = frag*512 + lane*8 + j):
//  Qf/Kf: frag(b, nt=n/32, ks=k/16): elem = M[nt*32+(lane&31)][ks*16+(lane>>5)*8+j]
//  Gf:    frag(b, ct=c/32, ms=m/16): elem = G[ct*32+(lane&31)][ms*16+(lane>>5)*8+j]
// ---------------------------------------------------------------------------

// xcast v2: coalesced fp32 read -> LDS transpose -> coalesced frag stores.
// block = (b, cg c32-group, mg 256-m-group); grid 16*8*9 = 1152.
__global__ __launch_bounds__(256) void xcast_kernel(
    const float* __restrict__ x, short* __restrict__ Gf)
{
  __shared__ short Xs[32][264];  // [c32][m256], +8 pad (16B-aligned rows)

  const int blk = blockIdx.x;
  const int mg  = blk % 9;
  const int cg  = (blk / 9) & 7;
  const int b   = blk / 72;
  const int t   = threadIdx.x;

  {
    const int cl = t >> 3, mch = (t & 7) * 32;
    const float* xp = x + ((size_t)(b * 256 + cg * 32 + cl)) * N_SP + mg * 256 + mch;
#pragma unroll
    for (int i = 0; i < 4; ++i) {
      float4 v0 = ((const float4*)xp)[2 * i];
      float4 v1 = ((const float4*)xp)[2 * i + 1];
      uint4 u;
      u.x = pk_bf16(v0.x, v0.y); u.y = pk_bf16(v0.z, v0.w);
      u.z = pk_bf16(v1.x, v1.y); u.w = pk_bf16(v1.z, v1.w);
      *(uint4*)&Xs[cl][mch + i * 8] = u;
    }
  }
  __syncthreads();

  const int lane = t & 63, l31 = lane & 31, h = lane >> 5;
#pragma unroll
  for (int it = 0; it < 4; ++it) {
    const int fi = it * 4 + (t >> 6);
    short8 v = *(const short8*)&Xs[l31][fi * 16 + h * 8];
    short* fb = Gf + ((size_t)(b * 8 + cg) * 144 + mg * 16 + fi) * 512 + lane * 8;
    *(short8*)fb = v;
  }
}

// ---------------------------------------------------------------------------
// proj: Qf/Kf = frag-layout bf16 of (W x + bias). Reads x via Gf frags.
// ---------------------------------------------------------------------------
__global__ __launch_bounds__(256) void proj_kernel(
    const short* __restrict__ Gf,
    const float* __restrict__ theta_w, const float* __restrict__ theta_b,
    const float* __restrict__ phi_w,   const float* __restrict__ phi_b,
    short* __restrict__ Qf, short* __restrict__ Kf)
{
  __shared__ short Xl[64][264];  // [n][c], +8 pad

  int b, nt;
  remap_bq(blockIdx.x, b, nt);
  const int n0 = nt * 64;
  const int t  = threadIdx.x;
  const int wave = t >> 6, lane = t & 63;
  const int l31 = lane & 31, h = lane >> 5;

  // ---- phase A: read 8 Gf frags/wave (coalesced), scatter to Xl[n][c] ----
#pragma unroll
  for (int i = 0; i < 2; ++i) {
    const int cgrp = wave * 2 + i;
    const int c = cgrp * 32 + l31;
#pragma unroll
    for (int s = 0; s < 4; ++s) {
      const short* fb = Gf + ((size_t)(b * 8 + cgrp) * 144 + (n0 >> 4) + s) * 512 + lane * 8;
      short8 v = *(const short8*)fb;
      const int nl = s * 16 + h * 8;
#pragma unroll
      for (int j = 0; j < 8; ++j) Xl[nl + j][c] = v[j];
    }
  }
  __syncthreads();

  // ---- GEMM: C[k][n] = W[k][:]·X[:][n], 16x16x32, wave owns 32 k-rows ----
  const int col = lane & 15, quad = lane >> 4;

  f32x4 acc[2][2][4];
#pragma unroll
  for (int p = 0; p < 2; ++p)
#pragma unroll
    for (int kr = 0; kr < 2; ++kr)
#pragma unroll
      for (int j = 0; j < 4; ++j) {
        acc[p][kr][j][0] = 0.f; acc[p][kr][j][1] = 0.f;
        acc[p][kr][j][2] = 0.f; acc[p][kr][j][3] = 0.f;
      }

#pragma unroll
  for (int cs = 0; cs < 8; ++cs) {
    const int c0 = cs * 32;
    short8 afr[2][2];
#pragma unroll
    for (int p = 0; p < 2; ++p) {
      const float* W = p ? phi_w : theta_w;
#pragma unroll
      for (int kr = 0; kr < 2; ++kr) {
        const int k = wave * 32 + kr * 16 + col;
        const float* wp = W + (size_t)k * C_IN + c0 + quad * 8;
        float4 w0 = ((const float4*)wp)[0];
        float4 w1 = ((const float4*)wp)[1];
        unsigned u[4];
        u[0] = pk_bf16(w0.x, w0.y); u[1] = pk_bf16(w0.z, w0.w);
        u[2] = pk_bf16(w1.x, w1.y); u[3] = pk_bf16(w1.z, w1.w);
        short8 a;
        __builtin_memcpy(&a, u, sizeof(a));
        afr[p][kr] = a;
      }
    }
#pragma unroll
    for (int j = 0; j < 4; ++j) {
      short8 bfr = *(const short8*)&Xl[j * 16 + col][c0 + quad * 8];
#pragma unroll
      for (int p = 0; p < 2; ++p)
#pragma unroll
        for (int kr = 0; kr < 2; ++kr)
          acc[p][kr][j] = __builtin_amdgcn_mfma_f32_16x16x32_bf16(
              afr[p][kr], bfr, acc[p][kr][j], 0, 0, 0);
    }
  }

  // ---- epilogue: bias + store in 32x32 fragment order ----
#pragma unroll
  for (int p = 0; p < 2; ++p) {
    const float* bias = p ? phi_b : theta_b;
    short* dst = p ? Kf : Qf;
#pragma unroll
    for (int kr = 0; kr < 2; ++kr) {
      const int ks = wave * 2 + kr;
      const int k0 = wave * 32 + kr * 16 + quad * 4;
      float4 bv = *(const float4*)(bias + k0);
#pragma unroll
      for (int j = 0; j < 4; ++j) {
        f32x4 v = acc[p][kr][j];
        uint2 sv;
        sv.x = pk_bf16(v[0] + bv.x, v[1] + bv.y);
        sv.y = pk_bf16(v[2] + bv.z, v[3] + bv.w);
        size_t addr = ((size_t)(b * 72 + (n0 >> 5) + (j >> 1)) * 8 + ks) * 512
                    + ((j & 1) * 16 + col + 32 * (quad >> 1)) * 8 + (quad & 1) * 4;
        *(uint2*)(dst + addr) = sv;
      }
    }
  }
}

// ---------------------------------------------------------------------------
// attn v4 = R8 + XCD swizzle + K reg-pipeline + batched G loads.
// Block: 64 q, 4 waves; wave w = m-quarter (S) and c-quarter (PV); m-tile 128.
// ---------------------------------------------------------------------------
__global__ __launch_bounds__(256, 2) void attn_kernel(
    const short* __restrict__ Qf, const short* __restrict__ Kf,
    const short* __restrict__ Gf, float* __restrict__ out)
{
  __shared__ short Pl[2][64][132];
  __shared__ float Ls[4][64];
  __shared__ float Linv[64];

  int b, qt;
  remap_bq(blockIdx.x, b, qt);
  const int qn0 = qt * 64;
  const int t = threadIdx.x, w = t >> 6, lane = t & 63;
  const int l31 = lane & 31, h = lane >> 5;

  // Q A-frags (q64 x k128), shared across waves via L1
  short8 qf[2][8];
  {
    const short* qb = Qf + ((size_t)(b * 72 + qt * 2) * 8) * 512 + lane * 8;
#pragma unroll
    for (int qj = 0; qj < 2; ++qj)
#pragma unroll
      for (int ks = 0; ks < 8; ++ks)
        qf[qj][ks] = *(const short8*)(qb + (qj * 8 + ks) * 512);
  }

  f32x16 yacc[2][2];  // [ct][qj]
#pragma unroll
  for (int a = 0; a < 2; ++a)
#pragma unroll
    for (int bb = 0; bb < 2; ++bb)
#pragma unroll
      for (int r = 0; r < 16; ++r) yacc[a][bb][r] = 0.f;
  float lsum[2][16];
#pragma unroll
  for (int qj = 0; qj < 2; ++qj)
#pragma unroll
    for (int r = 0; r < 16; ++r) lsum[qj][r] = 0.f;

  const short* kwb = Kf + (size_t)(b * 72) * 8 * 512 + lane * 8;
  const short* gwb = Gf + (size_t)(b * 8) * 144 * 512 + lane * 8;
  const float SC2 = 0.12754859f;  // (1/sqrt(128)) * log2(e)

  // K double-buffer: prefetch mt=0
  short8 kbuf[2][8];
  {
    const short* kf0 = kwb + (size_t)(w * 8) * 512;
#pragma unroll
    for (int ks = 0; ks < 8; ++ks) kbuf[0][ks] = *(const short8*)(kf0 + ks * 512);
  }

#pragma unroll 2
  for (int mt = 0; mt < MI; ++mt) {
    const int cur = mt & 1, nxt = cur ^ 1;
    const int mloc = w * 32 + l31;

    // ---- S + exp, qj=0 then qj=1 (halves s-register lifetime) ----
#pragma unroll
    for (int qj = 0; qj < 2; ++qj) {
      f32x16 s;
#pragma unroll
      for (int r = 0; r < 16; ++r) s[r] = 0.f;
#pragma unroll
      for (int ks = 0; ks < 8; ++ks)
        s = __builtin_amdgcn_mfma_f32_32x32x16_bf16(qf[qj][ks], kbuf[cur][ks], s, 0, 0, 0);
      if (qj == 1 && mt + 1 < MI) {  // prefetch next K tile after last use
        const short* kf1 = kwb + (size_t)(((mt + 1) * 4 + w) * 8) * 512;
#pragma unroll
        for (int ks = 0; ks < 8; ++ks)
          kbuf[nxt][ks] = *(const short8*)(kf1 + ks * 512);
      }
#pragma unroll
      for (int r = 0; r < 16; ++r) {
        float p = exp2f(s[r] * SC2);
        lsum[qj][r] += p;
        Pl[cur][qj * 32 + 4 * h + (r & 3) + 8 * (r >> 2)][mloc] =
            (short)(pk_bf16(p, p) & 0xffff);
      }
    }
    __syncthreads();

    // ---- PV: q64 x c64 over m128; G in batches of 8 frags ----
    const short* gw = gwb + (size_t)(w * 2 * 144 + mt * 8) * 512;
#pragma unroll
    for (int half = 0; half < 2; ++half) {
      short8 g[8];
#pragma unroll
      for (int ms = 0; ms < 4; ++ms)
#pragma unroll
        for (int ct = 0; ct < 2; ++ct)
          g[ms * 2 + ct] = *(const short8*)(gw + (size_t)(ct * 144 + half * 4 + ms) * 512);
#pragma unroll
      for (int ms = 0; ms < 4; ++ms) {
        short8 pfr[2];
#pragma unroll
        for (int qj = 0; qj < 2; ++qj) {
          const short* pp = &Pl[cur][qj * 32 + l31][(half * 4 + ms) * 16 + h * 8];
          uint2 lo = *(const uint2*)pp;
          uint2 hi = *(const uint2*)(pp + 4);
          unsigned uu[4] = {lo.x, lo.y, hi.x, hi.y};
          short8 pf;
          __builtin_memcpy(&pf, uu, sizeof(pf));
          pfr[qj] = pf;
        }
#pragma unroll
        for (int ct = 0; ct < 2; ++ct) {
          yacc[ct][0] = __builtin_amdgcn_mfma_f32_32x32x16_bf16(pfr[0], g[ms * 2 + ct], yacc[ct][0], 0, 0, 0);
          yacc[ct][1] = __builtin_amdgcn_mfma_f32_32x32x16_bf16(pfr[1], g[ms * 2 + ct], yacc[ct][1], 0, 0, 0);
        }
      }
    }
  }

  // ---- row-sum finalize ----
#pragma unroll
  for (int off = 1; off < 32; off <<= 1)
#pragma unroll
    for (int qj = 0; qj < 2; ++qj)
#pragma unroll
      for (int r = 0; r < 16; ++r) lsum[qj][r] += __shfl_xor(lsum[qj][r], off);
  if (l31 == 0) {
#pragma unroll
    for (int qj = 0; qj < 2; ++qj)
#pragma unroll
      for (int r = 0; r < 16; ++r)
        Ls[w][qj * 32 + 4 * h + (r & 3) + 8 * (r >> 2)] = lsum[qj][r];
  }
  __syncthreads();
  if (t < 64) Linv[t] = 1.0f / (Ls[0][t] + Ls[1][t] + Ls[2][t] + Ls[3][t]);
  __syncthreads();

  // ---- store ----
#pragma unroll
  for (int qj = 0; qj < 2; ++qj)
#pragma unroll
    for (int g = 0; g < 4; ++g) {
      const int nl = qj * 32 + 4 * h + 8 * g;
      float4 iv;
      iv.x = Linv[nl]; iv.y = Linv[nl + 1]; iv.z = Linv[nl + 2]; iv.w = Linv[nl + 3];
#pragma unroll
      for (int ct = 0; ct < 2; ++ct) {
        const int c = (w * 2 + ct) * 32 + l31;
        float4 v;
        v.x = yacc[ct][qj][4*g+0] * iv.x;
        v.y = yacc[ct][qj][4*g+1] * iv.y;
        v.z = yacc[ct][qj][4*g+2] * iv.z;
        v.w = yacc[ct][qj][4*g+3] * iv.w;
        *(float4*)(out + ((size_t)b * C_IN + c) * N_SP + qn0 + nl) = v;
      }
    }
}

extern "C" void kernel_launch(void* const* d_in, const int* in_sizes, int n_in,
                              void* d_out, int out_size, void* d_ws, size_t ws_size,
                              hipStream_t stream) {
  const float* x  = (const float*)d_in[0];
  const float* tw = (const float*)d_in[1];
  const float* tb = (const float*)d_in[2];
  const float* pw = (const float*)d_in[3];
  const float* pb = (const float*)d_in[4];
  float* out = (float*)d_out;

  // workspace: Qf (9.4MB) | Kf (9.4MB) | Gf (18.9MB) = 37.75 MB
  short* Qf = (short*)d_ws;
  short* Kf = Qf + (size_t)B_SZ * 72 * 8 * 512;
  short* Gf = Kf + (size_t)B_SZ * 72 * 8 * 512;

  xcast_kernel<<<B_SZ * 8 * 9, 256, 0, stream>>>(x, Gf);
  proj_kernel<<<B_SZ * NT64, 256, 0, stream>>>(Gf, tw, tb, pw, pb, Qf, Kf);
  attn_kernel<<<B_SZ * NT64, 256, 0, stream>>>(Qf, Kf, Gf, out);
}